// Round 15
// baseline (367.761 us; speedup 1.0000x reference)
//
#include <hip/hip_runtime.h>
#include <math.h>

#define NN 100000
#define NE 1600000
#define DI 256
#define DH 64
#define DO 47
#define DH3 48                      // h3s row stride: 192B -> 19.2 MB footprint
#define NB ((NN + 255) / 256)       // 391 scan blocks
#define RSZ8 ((NN + 7) / 8)         // 12500 nodes per XCD-pinned range
#define EPB 2048                    // edges per fill block
#define CPB ((NE + EPB - 1) / EPB)  // 782 chunks per range

// ---------------- degree, XCD-pinned ranges ----------------
__global__ __launch_bounds__(256) void k_degree(const int* __restrict__ dst,
                                                int* __restrict__ deg) {
    int r = blockIdx.x & 7;
    int chunk = blockIdx.x >> 3;
    int lo = r * RSZ8, hi = min(lo + RSZ8, NN);
    int base = chunk * EPB + threadIdx.x;
    #pragma unroll
    for (int i = 0; i < EPB / 256; ++i) {
        int e = base + i * 256;
        if (e < NE) {
            int d = dst[e];
            if (d >= lo && d < hi) atomicAdd(&deg[d], 1);
        }
    }
}

// ---------------- scan pass 1: per-block sums of deg ----------------
__global__ __launch_bounds__(256) void k_part(const int* __restrict__ deg,
                                              int* __restrict__ part) {
    int i = blockIdx.x * 256 + threadIdx.x;
    int v = (i < NN) ? deg[i] : 0;
    for (int off = 32; off; off >>= 1) v += __shfl_xor(v, off);
    __shared__ int s[4];
    if ((threadIdx.x & 63) == 0) s[threadIdx.x >> 6] = v;
    __syncthreads();
    if (threadIdx.x == 0) part[blockIdx.x] = s[0] + s[1] + s[2] + s[3];
}

// ---------------- scan pass 2: exclusive scan of partials (NB<=512) ----------------
__global__ __launch_bounds__(512) void k_scanpart(int* __restrict__ part) {
    int t = threadIdx.x, lane = t & 63, wv = t >> 6;
    int v0 = (t < NB) ? part[t] : 0;
    int v = v0;
    for (int off = 1; off < 64; off <<= 1) {
        int u = __shfl_up(v, off);
        if (lane >= off) v += u;
    }
    __shared__ int ws[8];
    if (lane == 63) ws[wv] = v;
    __syncthreads();
    if (t == 0) {
        int run = 0;
        for (int w = 0; w < 8; ++w) { int tmp = ws[w]; ws[w] = run; run += tmp; }
    }
    __syncthreads();
    v += ws[wv];
    if (t < NB) part[t] = v - v0;   // exclusive
}

// ---------------- scan pass 3: prefix -> rowptr, cursor; fused dinv ----------------
__global__ __launch_bounds__(256) void k_scan3(const int* __restrict__ deg,
                                               const int* __restrict__ part,
                                               int* __restrict__ rowptr,
                                               int* __restrict__ cursor,
                                               float* __restrict__ dinv) {
    int i = blockIdx.x * 256 + threadIdx.x;
    int lane = threadIdx.x & 63, wv = threadIdx.x >> 6;
    int v0 = (i < NN) ? deg[i] : 0;
    int v = v0;
    for (int off = 1; off < 64; off <<= 1) {
        int u = __shfl_up(v, off);
        if (lane >= off) v += u;
    }
    __shared__ int ws[4], wo[4];
    if (lane == 63) ws[wv] = v;
    __syncthreads();
    if (threadIdx.x == 0) {
        int run = 0;
        for (int w = 0; w < 4; ++w) { int tmp = ws[w]; wo[w] = run; run += tmp; }
    }
    __syncthreads();
    int excl = part[blockIdx.x] + wo[wv] + v - v0;
    if (i < NN) {
        rowptr[i] = excl;
        cursor[i] = excl;
        dinv[i] = rsqrtf((float)(v0 + 1));
    }
}

// ---------------- bucket-fill, XCD-pinned ranges ----------------
__global__ __launch_bounds__(256) void k_fillr(const int* __restrict__ src,
                                               const int* __restrict__ dst,
                                               int* __restrict__ cursor,
                                               int* __restrict__ csr_src) {
    int r = blockIdx.x & 7;
    int chunk = blockIdx.x >> 3;
    int lo = r * RSZ8, hi = min(lo + RSZ8, NN);
    int base = chunk * EPB + threadIdx.x;
    #pragma unroll
    for (int i = 0; i < EPB / 256; ++i) {
        int e = base + i * 256;
        if (e < NE) {
            int d = dst[e];
            if (d >= lo && d < hi) {
                int p = atomicAdd(&cursor[d], 1);
                csr_src[p] = src[e];
            }
        }
    }
}

// ---------------- h1s = dinv * (x @ W1), register-blocked 2 rows/lane ----------------
__global__ __launch_bounds__(512) void k_gemm1(const float* __restrict__ x,
                                               const float* __restrict__ W1,
                                               const float* __restrict__ dinv,
                                               float* __restrict__ h1s) {
    __shared__ float xs[2][128 * 33];  // 33.8 KB
    __shared__ float wl[2][32 * 64];   // 16 KB   -> 50 KB total, 3 blocks/CU
    const int t = threadIdx.x;
    const int lane = t & 63;
    const int wvu = __builtin_amdgcn_readfirstlane(t >> 6);
    const int r0 = blockIdx.x * 128;
    const int sr = t >> 2;             // x staging: 4 threads/row (0..127)
    const int sk = (t & 3) * 8;        // 2 float4 at sk, sk+4
    const int wk = t >> 4;             // W staging: chunk row 0..31
    const int wc = (t & 15) * 4;       // col quad
    const long xrow = (long)min(r0 + sr, NN - 1) * DI;
    const int rowA = r0 + lane;
    const int rowB = r0 + 64 + lane;

    float accA[8] = {0.f, 0.f, 0.f, 0.f, 0.f, 0.f, 0.f, 0.f};
    float accB[8] = {0.f, 0.f, 0.f, 0.f, 0.f, 0.f, 0.f, 0.f};

    {   // stage chunk 0 (x + W)
        float4 v0 = *(const float4*)(x + xrow + sk);
        float4 v1 = *(const float4*)(x + xrow + sk + 4);
        float* p = &xs[0][sr * 33 + sk];
        p[0] = v0.x; p[1] = v0.y; p[2] = v0.z; p[3] = v0.w;
        p[4] = v1.x; p[5] = v1.y; p[6] = v1.z; p[7] = v1.w;
        float4 w = *(const float4*)(W1 + (size_t)wk * DH + wc);
        float* q = &wl[0][wk * 64 + wc];
        q[0] = w.x; q[1] = w.y; q[2] = w.z; q[3] = w.w;
    }
    __syncthreads();
    for (int c = 0; c < 8; ++c) {
        const int buf = c & 1;
        if (c + 1 < 8) {   // stage next chunk into other buffer
            float4 v0 = *(const float4*)(x + xrow + (c + 1) * 32 + sk);
            float4 v1 = *(const float4*)(x + xrow + (c + 1) * 32 + sk + 4);
            float* p = &xs[buf ^ 1][sr * 33 + sk];
            p[0] = v0.x; p[1] = v0.y; p[2] = v0.z; p[3] = v0.w;
            p[4] = v1.x; p[5] = v1.y; p[6] = v1.z; p[7] = v1.w;
            float4 w = *(const float4*)(W1 + (size_t)((c + 1) * 32 + wk) * DH + wc);
            float* q = &wl[buf ^ 1][wk * 64 + wc];
            q[0] = w.x; q[1] = w.y; q[2] = w.z; q[3] = w.w;
        }
        #pragma unroll 4
        for (int kk = 0; kk < 32; ++kk) {
            float xa = xs[buf][lane * 33 + kk];
            float xb = xs[buf][(lane + 64) * 33 + kk];
            const float4* wp = (const float4*)&wl[buf][kk * 64 + wvu * 8];
            float4 wa = wp[0], wb = wp[1];
            accA[0] += wa.x * xa; accA[1] += wa.y * xa;
            accA[2] += wa.z * xa; accA[3] += wa.w * xa;
            accA[4] += wb.x * xa; accA[5] += wb.y * xa;
            accA[6] += wb.z * xa; accA[7] += wb.w * xa;
            accB[0] += wa.x * xb; accB[1] += wa.y * xb;
            accB[2] += wa.z * xb; accB[3] += wa.w * xb;
            accB[4] += wb.x * xb; accB[5] += wb.y * xb;
            accB[6] += wb.z * xb; accB[7] += wb.w * xb;
        }
        __syncthreads();
    }
    if (rowA < NN) {
        float di = dinv[rowA];
        float4 o0 = {di * accA[0], di * accA[1], di * accA[2], di * accA[3]};
        float4 o1 = {di * accA[4], di * accA[5], di * accA[6], di * accA[7]};
        float4* hp = (float4*)(h1s + (long)rowA * DH + wvu * 8);
        hp[0] = o0;
        hp[1] = o1;
    }
    if (rowB < NN) {
        float di = dinv[rowB];
        float4 o0 = {di * accB[0], di * accB[1], di * accB[2], di * accB[3]};
        float4 o1 = {di * accB[4], di * accB[5], di * accB[6], di * accB[7]};
        float4* hp = (float4*)(h1s + (long)rowB * DH + wvu * 8);
        hp[0] = o0;
        hp[1] = o1;
    }
}

// ---------------- layer1 gather (4 rows/wave, unmasked main loop) ----------------
// Main loop to min(cnt): no clamp, no mask (indices provably valid).
// Tail to max(cnt): clamped + masked. 32-bit gather indices (max 6.4M).
__global__ __launch_bounds__(256) void k_agg1(const int* __restrict__ rowptr,
                                              const int* __restrict__ deg,
                                              const int* __restrict__ csr_src,
                                              const float* __restrict__ dinv,
                                              const float* __restrict__ h1s,
                                              const float* __restrict__ b1,
                                              const float* __restrict__ W2,
                                              float* __restrict__ h3s) {
    __shared__ float w2[DH * DO];   // 12 KB
    __shared__ float sh[16][DH];    // 4 KB
    for (int i = threadIdx.x; i < DH * DO; i += 256) w2[i] = W2[i];
    __syncthreads();
    const int wv = threadIdx.x >> 6, lane = threadIdx.x & 63;
    const int rbase = blockIdx.x * 16 + wv * 4;
    int beg[4], cnt[4];
    float acc[4] = {0.f, 0.f, 0.f, 0.f};
    #pragma unroll
    for (int r = 0; r < 4; ++r) {
        beg[r] = rowptr[rbase + r];
        cnt[r] = deg[rbase + r];
    }
    const int cmin = min(min(cnt[0], cnt[1]), min(cnt[2], cnt[3]));
    const int tmax = max(max(cnt[0], cnt[1]), max(cnt[2], cnt[3]));
    int j = 0;
    for (; j + 3 < cmin; j += 4) {          // unmasked main: 16 gathers in flight
        #pragma unroll
        for (int k = 0; k < 4; ++k) {
            #pragma unroll
            for (int r = 0; r < 4; ++r) {
                unsigned s = (unsigned)csr_src[beg[r] + j + k];
                acc[r] += h1s[s * (unsigned)DH + lane];
            }
        }
    }
    for (; j < tmax; j += 4) {              // clamped + masked tail
        #pragma unroll
        for (int k = 0; k < 4; ++k) {
            #pragma unroll
            for (int r = 0; r < 4; ++r) {
                unsigned s = (unsigned)csr_src[min(beg[r] + j + k, NE - 1)];
                float v = h1s[s * (unsigned)DH + lane];
                acc[r] += (j + k < cnt[r]) ? v : 0.f;
            }
        }
    }
    float di[4];
    #pragma unroll
    for (int r = 0; r < 4; ++r) {
        di[r] = dinv[rbase + r];
        float v = di[r] * (acc[r] + h1s[(unsigned)(rbase + r) * DH + lane]) + b1[lane];
        sh[wv * 4 + r][lane] = fmaxf(v, 0.f);
    }
    __syncthreads();
    if (lane < DO) {
        float o[4] = {0.f, 0.f, 0.f, 0.f};
        #pragma unroll 8
        for (int k = 0; k < DH; ++k) {
            float w = w2[k * DO + lane];
            #pragma unroll
            for (int r = 0; r < 4; ++r) o[r] += sh[wv * 4 + r][k] * w;
        }
        #pragma unroll
        for (int r = 0; r < 4; ++r)
            h3s[(unsigned)(rbase + r) * DH3 + lane] = di[r] * o[r];
    }
}

// ---------------- layer2 gather (4 rows/wave, unmasked main) + softmax/argmax ----------------
__global__ __launch_bounds__(256) void k_agg2(const int* __restrict__ rowptr,
                                              const int* __restrict__ deg,
                                              const int* __restrict__ csr_src,
                                              const float* __restrict__ dinv,
                                              const float* __restrict__ h3s,
                                              const float* __restrict__ b2,
                                              float* __restrict__ logits,
                                              float* __restrict__ preds,
                                              float* __restrict__ xo) {
    const int wv = threadIdx.x >> 6, lane = threadIdx.x & 63;
    const int rbase = blockIdx.x * 16 + wv * 4;
    const bool act = lane < DO;
    const unsigned lx = act ? (unsigned)lane : 0u;
    int beg[4], cnt[4];
    float acc[4] = {0.f, 0.f, 0.f, 0.f};
    #pragma unroll
    for (int r = 0; r < 4; ++r) {
        beg[r] = rowptr[rbase + r];
        cnt[r] = deg[rbase + r];
    }
    const int cmin = min(min(cnt[0], cnt[1]), min(cnt[2], cnt[3]));
    const int tmax = max(max(cnt[0], cnt[1]), max(cnt[2], cnt[3]));
    int j = 0;
    for (; j + 3 < cmin; j += 4) {
        #pragma unroll
        for (int k = 0; k < 4; ++k) {
            #pragma unroll
            for (int r = 0; r < 4; ++r) {
                unsigned s = (unsigned)csr_src[beg[r] + j + k];
                acc[r] += h3s[s * (unsigned)DH3 + lx];
            }
        }
    }
    for (; j < tmax; j += 4) {
        #pragma unroll
        for (int k = 0; k < 4; ++k) {
            #pragma unroll
            for (int r = 0; r < 4; ++r) {
                unsigned s = (unsigned)csr_src[min(beg[r] + j + k, NE - 1)];
                float v = h3s[s * (unsigned)DH3 + lx];
                acc[r] += (j + k < cnt[r]) ? v : 0.f;
            }
        }
    }
    float val[4];
    #pragma unroll
    for (int r = 0; r < 4; ++r) {
        float di = dinv[rbase + r];
        val[r] = act ? di * (acc[r] + h3s[(unsigned)(rbase + r) * DH3 + lane]) + b2[lane]
                     : -INFINITY;
        if (act) xo[(size_t)(rbase + r) * DO + lane] = val[r];
    }
    float m[4] = {val[0], val[1], val[2], val[3]};
    for (int off = 32; off; off >>= 1) {
        #pragma unroll
        for (int r = 0; r < 4; ++r) m[r] = fmaxf(m[r], __shfl_xor(m[r], off));
    }
    int idx[4];
    #pragma unroll
    for (int r = 0; r < 4; ++r) idx[r] = (act && val[r] == m[r]) ? lane : (1 << 30);
    for (int off = 32; off; off >>= 1) {
        #pragma unroll
        for (int r = 0; r < 4; ++r) idx[r] = min(idx[r], __shfl_xor(idx[r], off));
    }
    float ev[4], ss[4];
    #pragma unroll
    for (int r = 0; r < 4; ++r) { ev[r] = act ? expf(val[r] - m[r]) : 0.f; ss[r] = ev[r]; }
    for (int off = 32; off; off >>= 1) {
        #pragma unroll
        for (int r = 0; r < 4; ++r) ss[r] += __shfl_xor(ss[r], off);
    }
    if (act) {
        #pragma unroll
        for (int r = 0; r < 4; ++r)
            logits[(size_t)(rbase + r) * DO + lane] = ev[r] / ss[r];
    }
    if (lane == 0) {
        #pragma unroll
        for (int r = 0; r < 4; ++r) preds[rbase + r] = (float)idx[r];
    }
}

extern "C" void kernel_launch(void* const* d_in, const int* in_sizes, int n_in,
                              void* d_out, int out_size, void* d_ws, size_t ws_size,
                              hipStream_t stream) {
    const float* x  = (const float*)d_in[0];
    const int*   ei = (const int*)d_in[1];
    const float* W1 = (const float*)d_in[2];
    const float* b1 = (const float*)d_in[3];
    const float* W2 = (const float*)d_in[4];
    const float* b2 = (const float*)d_in[5];
    const int* src = ei;          // edge_index[0]
    const int* dst = ei + NE;     // edge_index[1]

    float* out    = (float*)d_out;
    float* logits = out;                      // [N,47]
    float* preds  = out + (size_t)NN * DO;    // [N]
    float* xo     = preds + NN;               // [N,47]

    // workspace layout (~53 MB)
    char* wsb = (char*)d_ws;
    int*   deg     = (int*)wsb;                         wsb += (size_t)NN * 4;
    float* dinv    = (float*)wsb;                       wsb += (size_t)NN * 4;
    int*   rowptr  = (int*)wsb;                         wsb += (size_t)NN * 4;
    int*   cursor  = (int*)wsb;                         wsb += (size_t)NN * 4;
    int*   part    = (int*)wsb;                         wsb += (size_t)512 * 4;
    int*   csr_src = (int*)wsb;                         wsb += (size_t)NE * 4;
    float* h1s     = (float*)wsb;                       wsb += (size_t)NN * DH * 4;
    float* h3s     = (float*)wsb;                       wsb += (size_t)NN * DH3 * 4;

    hipMemsetAsync(deg, 0, NN * sizeof(int), stream);

    k_degree<<<8 * CPB, 256, 0, stream>>>(dst, deg);
    k_part<<<NB, 256, 0, stream>>>(deg, part);
    k_scanpart<<<1, 512, 0, stream>>>(part);
    k_scan3<<<NB, 256, 0, stream>>>(deg, part, rowptr, cursor, dinv);
    k_fillr<<<8 * CPB, 256, 0, stream>>>(src, dst, cursor, csr_src);
    k_gemm1<<<(NN + 127) / 128, 512, 0, stream>>>(x, W1, dinv, h1s);
    k_agg1<<<NN / 16, 256, 0, stream>>>(rowptr, deg, csr_src, dinv, h1s, b1, W2, h3s);
    k_agg2<<<NN / 16, 256, 0, stream>>>(rowptr, deg, csr_src, dinv, h3s, b2, logits, preds, xo);
}